// Round 9
// baseline (5891.996 us; speedup 1.0000x reference)
//
#include <hip/hip_runtime.h>

typedef __attribute__((ext_vector_type(4))) float  f32x4;
typedef __attribute__((ext_vector_type(8))) short  bf16x8;

#define NTHR 1024
#define BT   128
#define L2E  1.4426950408889634f

// ---------------- LDS byte map (total 161168 <= 163840) ----------------
// planes: [layer][split] 16384B each: [128 elems][64 units] bf16, XOR-swizzled
#define PLANE(L,S) ((L)*32768 + (S)*16384)
#define QBUFP(p)   (98304 + ((p)<<14))     // 2 parity-rotating 16KB stage buffers
#define XFB_OFF    131072                  // [128][4] f32 feedback x, 16B stride (2048B)
#define Y1_OFF     133120                  // [128][34] bf16 (8704B)
#define Y2_OFF     141824                  // [128][18] bf16 (4608B)
#define W2L_OFF    146432                  // [16][32] bf16 (1024B)
#define BGL_OFF    147456                  // [3][256] f32 bias sums, log2e-scaled (3072B)
#define B1L_OFF    150528                  // [32] f32
#define B2L_OFF    150656                  // [16] f32
#define B3L_OFF    150720                  // [4] f32
#define W3L_OFF    150736                  // [3][16] f32 (192B)
#define W0L_OFF    150928                  // [256][4] f32, 16B stride, log2e-scaled (4096B)
#define OUT_OFF    155024                  // [128][12] f32 out ring, 4 steps (6144B)
#define LDS_TOTAL  161168

// frag-ordered split weights (gate mats log2e-prescaled): 5 mats * 64KB + w1 8KB
__device__ __align__(16) unsigned char g_wsbuf[335872];

__device__ __forceinline__ unsigned short f2bf(float v) {
    unsigned int x = __float_as_uint(v);
    unsigned int r = x + 0x7fffu + ((x >> 16) & 1u);
    return (unsigned short)(r >> 16);
}
__device__ __forceinline__ float bf2f_lo(unsigned int d) { return __uint_as_float(d << 16); }
__device__ __forceinline__ float bf2f_hi(unsigned int d) { return __uint_as_float(d & 0xffff0000u); }

// packed f32->bf16 pair (src0 -> low half). No builtin on gfx950 (m240) — inline asm.
__device__ __forceinline__ unsigned int cvtpk(float a, float b) {
    unsigned int r;
    asm("v_cvt_pk_bf16_f32 %0, %1, %2" : "=v"(r) : "v"(a), "v"(b));
    return r;
}

// gates pre-scaled by log2e (2*log2e for g-gate): pure exp2 forms
__device__ __forceinline__ float fsig2(float y) {   // sigmoid(x), y = x*log2e
    return __builtin_amdgcn_rcpf(1.0f + __builtin_amdgcn_exp2f(-y));
}
__device__ __forceinline__ float ftanh2(float y) {  // tanh(x), y = 2x*log2e
    return 1.0f - 2.0f * __builtin_amdgcn_rcpf(1.0f + __builtin_amdgcn_exp2f(y));
}
__device__ __forceinline__ float ftanhc(float c) {  // tanh(c), c true-scale
    return 1.0f - 2.0f * __builtin_amdgcn_rcpf(1.0f + __builtin_amdgcn_exp2f(c * (2.0f * L2E)));
}

// ---------------- prologue: frag-order + split + log2e prescale ----------------
__global__ void prep_weights(const float* __restrict__ whh0, const float* __restrict__ wih1,
                             const float* __restrict__ whh1, const float* __restrict__ wih2,
                             const float* __restrict__ whh2, const float* __restrict__ w1g)
{
    int gi = blockIdx.x * 256 + threadIdx.x;
    if (gi < 20480) {
        int m = gi >> 12;
        int rem = gi & 4095;
        int b = rem >> 6, l = rem & 63;
        int s = b & 1, ks = (b >> 1) & 1, g = (b >> 2) & 3, ug = b >> 4;
        int row = g * 64 + ug * 16 + (l & 15);
        int kb  = ks * 32 + (l >> 4) * 8;
        float fac = (g == 2) ? (2.0f * L2E) : L2E;
        const float* src = (m == 0) ? whh0 : (m == 1) ? wih1 : (m == 2) ? whh1
                         : (m == 3) ? wih2 : whh2;
        unsigned short o[8];
        #pragma unroll
        for (int i = 0; i < 8; ++i) {
            float v = src[row * 64 + kb + i] * fac;
            unsigned short hh = f2bf(v);
            if (s) {
                float r2 = v - __uint_as_float((unsigned int)hh << 16);
                hh = f2bf(r2);
            }
            o[i] = hh;
        }
        unsigned char* dst = g_wsbuf + m * 65536 + b * 1024 + l * 16;
        #pragma unroll
        for (int i = 0; i < 8; ++i) ((unsigned short*)dst)[i] = o[i];
    } else if (gi < 20992) {
        int g2 = gi - 20480;
        int b = g2 >> 6, l = g2 & 63;
        int s = b & 1, ks = (b >> 1) & 1, nt = b >> 2;
        int row = nt * 16 + (l & 15);
        int kb  = ks * 32 + (l >> 4) * 8;
        unsigned short o[8];
        #pragma unroll
        for (int i = 0; i < 8; ++i) {
            float v = w1g[row * 64 + kb + i];           // w1: unscaled
            unsigned short hh = f2bf(v);
            if (s) {
                float r2 = v - __uint_as_float((unsigned int)hh << 16);
                hh = f2bf(r2);
            }
            o[i] = hh;
        }
        unsigned char* dst = g_wsbuf + 327680 + b * 1024 + l * 16;
        #pragma unroll
        for (int i = 0; i < 8; ++i) ((unsigned short*)dst)[i] = o[i];
    }
}

#define MFMA_(A,B,C) __builtin_amdgcn_mfma_f32_16x16x32_bf16(A, B, C, 0, 0, 0)

// phase barrier: LDS producer drain -> barrier -> compiler memory fence.
// No sched_barrier(0) (m141: order-pinning defeats the scheduler); the post-barrier
// asm memory clobber blocks hoisting reads above the barrier (m201 pattern).
#define BARX do { \
    asm volatile("s_waitcnt lgkmcnt(0)" ::: "memory"); \
    __builtin_amdgcn_s_barrier(); \
    asm volatile("" ::: "memory"); \
    } while (0)

// 1024-thread staging: one dwordx4 per thread per 16KB quarter.
#define LOADQ(m, ks, s, R) \
    R = *(const bf16x8*)(g_wsbuf + (m) * 65536 + \
        (((tid >> 6) * 4 + (ks) * 2 + (s))) * 1024 + (tid & 63) * 16)
#define COMMITQ(R, p) \
    *(bf16x8*)(lds + QBUFP(p) + tid * 16) = R
#define LOADW1(R) do { if (tid < 512) \
    R = *(const bf16x8*)(g_wsbuf + 327680 + (tid >> 6) * 1024 + (tid & 63) * 16); } while (0)
#define COMMITW1(R, p) do { if (tid < 512) \
    *(bf16x8*)(lds + QBUFP(p) + tid * 16) = R; } while (0)

#define ACC_INIT(L) do { \
    _Pragma("unroll") for (int g_ = 0; g_ < 4; ++g_) { \
        float b_ = *(const float*)(lds + BGL_OFF + ((L) * 256 + g_ * 64 + u) * 4); \
        f32x4 t_ = {b_, b_, b_, b_}; \
        _Pragma("unroll") for (int mt_ = 0; mt_ < 2; ++mt_) acc[g_][mt_] = t_; \
    } } while (0)

#define GATE_HI(APL, ks, P) do { \
    bf16x8 bh_[4]; \
    _Pragma("unroll") for (int g_ = 0; g_ < 4; ++g_) \
        bh_[g_] = *(const bf16x8*)(lds + QBUFP(P) + (ug * 4 + g_) * 1024 + lane * 16); \
    _Pragma("unroll") for (int mt_ = 0; mt_ < 2; ++mt_) { \
        int ab_ = (((mbase + mt_ * 16 + l15) * 128 + (ks) * 64 + l4 * 16)) ^ rswz; \
        bf16x8 ah_ = *(const bf16x8*)(lds + PLANE(APL, 0) + ab_); \
        bf16x8 al_ = *(const bf16x8*)(lds + PLANE(APL, 1) + ab_); \
        _Pragma("unroll") for (int g_ = 0; g_ < 4; ++g_) { \
            acc[g_][mt_] = MFMA_(ah_, bh_[g_], acc[g_][mt_]); \
            acc[g_][mt_] = MFMA_(al_, bh_[g_], acc[g_][mt_]); \
        } } } while (0)

#define GATE_LO(APL, ks, P) do { \
    bf16x8 bl_[4]; \
    _Pragma("unroll") for (int g_ = 0; g_ < 4; ++g_) \
        bl_[g_] = *(const bf16x8*)(lds + QBUFP(P) + (ug * 4 + g_) * 1024 + lane * 16); \
    _Pragma("unroll") for (int mt_ = 0; mt_ < 2; ++mt_) { \
        int ab_ = (((mbase + mt_ * 16 + l15) * 128 + (ks) * 64 + l4 * 16)) ^ rswz; \
        bf16x8 ah_ = *(const bf16x8*)(lds + PLANE(APL, 0) + ab_); \
        _Pragma("unroll") for (int g_ = 0; g_ < 4; ++g_) \
            acc[g_][mt_] = MFMA_(ah_, bl_[g_], acc[g_][mt_]); \
    } } while (0)

// cell + packed hi/lo bf16 h-plane writes (v_cvt_pk_bf16_f32; split compensates rounding)
#define CELLW(L, CARR) do { \
    _Pragma("unroll") for (int mt_ = 0; mt_ < 2; ++mt_) { \
        float hn_[4]; \
        _Pragma("unroll") for (int r_ = 0; r_ < 4; ++r_) { \
            float gi_ = fsig2(acc[0][mt_][r_]); \
            float gf_ = fsig2(acc[1][mt_][r_]); \
            float gg_ = ftanh2(acc[2][mt_][r_]); \
            float go_ = fsig2(acc[3][mt_][r_]); \
            float cn_ = gf_ * CARR[mt_ * 4 + r_] + gi_ * gg_; \
            CARR[mt_ * 4 + r_] = cn_; \
            hn_[r_] = go_ * ftanhc(cn_); \
        } \
        _Pragma("unroll") for (int pr_ = 0; pr_ < 2; ++pr_) { \
            float a_ = hn_[pr_ * 2], b_ = hn_[pr_ * 2 + 1]; \
            unsigned int ph_ = cvtpk(a_, b_); \
            float fa_ = __uint_as_float(ph_ << 16); \
            float fb_ = __uint_as_float(ph_ & 0xffff0000u); \
            unsigned int pl_ = cvtpk(a_ - fa_, b_ - fb_); \
            int e0_ = mbase + mt_ * 16 + l4 * 4 + pr_ * 2; \
            int e1_ = e0_ + 1; \
            int wb0_ = ((e0_ * 128 + u * 2)) ^ ((e0_ & 7) << 4); \
            int wb1_ = ((e1_ * 128 + u * 2)) ^ ((e1_ & 7) << 4); \
            *(unsigned short*)(lds + PLANE(L, 0) + wb0_) = (unsigned short)ph_; \
            *(unsigned short*)(lds + PLANE(L, 0) + wb1_) = (unsigned short)(ph_ >> 16); \
            *(unsigned short*)(lds + PLANE(L, 1) + wb0_) = (unsigned short)pl_; \
            *(unsigned short*)(lds + PLANE(L, 1) + wb1_) = (unsigned short)(pl_ >> 16); \
        } \
    } } while (0)

#define XPART do { \
    _Pragma("unroll") for (int mt_ = 0; mt_ < 2; ++mt_) \
    _Pragma("unroll") for (int r_ = 0; r_ < 4; ++r_) { \
        int e_ = mbase + mt_ * 16 + l4 * 4 + r_; \
        f32x4 xv_ = *(const f32x4*)(lds + XFB_OFF + e_ * 16); \
        _Pragma("unroll") for (int g_ = 0; g_ < 4; ++g_) { \
            f32x4 w0_ = *(const f32x4*)(lds + W0L_OFF + (g_ * 64 + u) * 16); \
            acc[g_][mt_][r_] += xv_.x * w0_.x + xv_.y * w0_.y + xv_.z * w0_.z; \
        } } } while (0)

#define MLP1(P) do { \
    int Mt_ = wv >> 1, half_ = wv & 1; \
    float b1_ = *(const float*)(lds + B1L_OFF + (half_ * 16 + l15) * 4); \
    f32x4 a1_ = {b1_, b1_, b1_, b1_}; \
    _Pragma("unroll") for (int ks_ = 0; ks_ < 2; ++ks_) { \
        int ab_ = (((Mt_ * 16 + l15) * 128 + ks_ * 64 + l4 * 16)) ^ rswz; \
        bf16x8 ah_ = *(const bf16x8*)(lds + PLANE(2, 0) + ab_); \
        bf16x8 al_ = *(const bf16x8*)(lds + PLANE(2, 1) + ab_); \
        bf16x8 wh_ = *(const bf16x8*)(lds + QBUFP(P) + ((half_ * 2 + ks_) * 2 + 0) * 1024 + lane * 16); \
        bf16x8 wl_ = *(const bf16x8*)(lds + QBUFP(P) + ((half_ * 2 + ks_) * 2 + 1) * 1024 + lane * 16); \
        a1_ = MFMA_(ah_, wh_, a1_); \
        a1_ = MFMA_(al_, wh_, a1_); \
        a1_ = MFMA_(ah_, wl_, a1_); \
    } \
    _Pragma("unroll") for (int r_ = 0; r_ < 4; ++r_) { \
        float y_ = a1_[r_]; y_ = (y_ >= 0.f) ? y_ : 0.01f * y_; \
        int e_ = Mt_ * 16 + l4 * 4 + r_; \
        *(unsigned short*)(lds + Y1_OFF + e_ * 68 + half_ * 32 + l15 * 2) = f2bf(y_); \
    } } while (0)

#define MLP2 do { \
    int e2_ = tid & 127, rg_ = tid >> 7; \
    float a2_[2]; \
    _Pragma("unroll") for (int m_ = 0; m_ < 2; ++m_) \
        a2_[m_] = *(const float*)(lds + B2L_OFF + (rg_ * 2 + m_) * 4); \
    _Pragma("unroll") for (int kd_ = 0; kd_ < 16; ++kd_) { \
        unsigned int d_ = *(const unsigned int*)(lds + Y1_OFF + e2_ * 68 + kd_ * 4); \
        float v0_ = bf2f_lo(d_), v1_ = bf2f_hi(d_); \
        _Pragma("unroll") for (int m_ = 0; m_ < 2; ++m_) { \
            unsigned int w_ = *(const unsigned int*)(lds + W2L_OFF + ((rg_ * 2 + m_) * 32 + kd_ * 2) * 2); \
            a2_[m_] = fmaf(v0_, bf2f_lo(w_), a2_[m_]); \
            a2_[m_] = fmaf(v1_, bf2f_hi(w_), a2_[m_]); \
        } } \
    _Pragma("unroll") for (int m_ = 0; m_ < 2; ++m_) { \
        float y_ = a2_[m_]; y_ = (y_ >= 0.f) ? y_ : 0.01f * y_; \
        *(unsigned short*)(lds + Y2_OFF + e2_ * 36 + (rg_ * 2 + m_) * 2) = f2bf(y_); \
    } } while (0)

#define MLP3_OUT do { \
    if (tid < 384) { \
        int e3_ = tid & 127, r3_ = tid >> 7; \
        float a3_ = *(const float*)(lds + B3L_OFF + r3_ * 4); \
        _Pragma("unroll") for (int kd_ = 0; kd_ < 8; ++kd_) { \
            unsigned int d_ = *(const unsigned int*)(lds + Y2_OFF + e3_ * 36 + kd_ * 4); \
            a3_ = fmaf(bf2f_lo(d_), *(const float*)(lds + W3L_OFF + (r3_ * 16 + kd_ * 2) * 4),     a3_); \
            a3_ = fmaf(bf2f_hi(d_), *(const float*)(lds + W3L_OFF + (r3_ * 16 + kd_ * 2 + 1) * 4), a3_); \
        } \
        float y_ = (a3_ >= 0.f) ? a3_ : 0.01f * a3_; \
        *(float*)(lds + XFB_OFF + e3_ * 16 + r3_ * 4) = y_; \
        *(float*)(lds + OUT_OFF + e3_ * 48 + (t & 3) * 12 + r3_ * 4) = y_; \
    } } while (0)

// ---------------- main persistent kernel ----------------
extern "C" __global__ void __launch_bounds__(NTHR)
__attribute__((amdgpu_waves_per_eu(4, 4)))
lstm_mfma(const float* __restrict__ noise,
          const float* __restrict__ wih0, const float* __restrict__ whh0,
          const float* __restrict__ bih0, const float* __restrict__ bhh0,
          const float* __restrict__ wih1, const float* __restrict__ whh1,
          const float* __restrict__ bih1, const float* __restrict__ bhh1,
          const float* __restrict__ wih2, const float* __restrict__ whh2,
          const float* __restrict__ bih2, const float* __restrict__ bhh2,
          const float* __restrict__ w1g, const float* __restrict__ b1g,
          const float* __restrict__ w2g, const float* __restrict__ b2g,
          const float* __restrict__ w3g, const float* __restrict__ b3g,
          const int* __restrict__ lenp, float* __restrict__ out)
{
    extern __shared__ unsigned char lds[];
    const int tid  = threadIdx.x;
    const int lane = tid & 63;
    const int wv   = tid >> 6;       // wave 0..15
    const int ug   = wv & 3;         // unit group (16 units)
    const int mh   = wv >> 2;        // M quarter 0..3
    const int l15  = lane & 15;
    const int l4   = lane >> 4;      // k-group
    const int u    = ug * 16 + l15;  // unit 0..63
    const int mbase = mh * 32;
    const int rswz  = (lane & 7) << 4;
    const int T = *lenp;
    const long eg0  = (long)blockIdx.x * BT;
    const long outs = 3L * T;

    // per-thread recurrent c state: 8 (unit,elem) pairs per layer
    float c0[8], c1[8], c2[8];
    #pragma unroll
    for (int i = 0; i < 8; ++i) { c0[i] = 0.f; c1[i] = 0.f; c2[i] = 0.f; }

    // staging registers (3-deep rotation)
    bf16x8 RA, RB, RC;

    // issue warmup loads early (q0,q1,q2)
    LOADQ(0, 0, 0, RA);
    LOADQ(0, 1, 0, RB);
    LOADQ(0, 0, 1, RC);

    // ---- LDS init ----
    for (int i = tid; i < 98304 / 4; i += NTHR) ((unsigned int*)lds)[i] = 0u;  // h planes = 0
    if (tid < BT) {
        const float* np = noise + (eg0 + tid) * 3;
        f32x4 xv = {np[0], np[1], np[2], 0.f};
        *(f32x4*)(lds + XFB_OFF + tid * 16) = xv;
    }
    if (tid < 512) *(unsigned short*)(lds + W2L_OFF + tid * 2) = f2bf(w2g[tid]);
    if (tid < 768) {                                   // bias sums, log2e-scaled
        int l = tid >> 8, r = tid & 255, g = r >> 6;
        float fac = (g == 2) ? (2.0f * L2E) : L2E;
        const float* bi = (l == 0) ? bih0 : ((l == 1) ? bih1 : bih2);
        const float* bh = (l == 0) ? bhh0 : ((l == 1) ? bhh1 : bhh2);
        *(float*)(lds + BGL_OFF + tid * 4) = (bi[r] + bh[r]) * fac;
    }
    if (tid < 256) {                                   // wih0, log2e-scaled, 16B stride
        int g = tid >> 6;
        float fac = (g == 2) ? (2.0f * L2E) : L2E;
        f32x4 wv0 = {wih0[tid * 3] * fac, wih0[tid * 3 + 1] * fac,
                     wih0[tid * 3 + 2] * fac, 0.f};
        *(f32x4*)(lds + W0L_OFF + tid * 16) = wv0;
    }
    if (tid < 32) *(float*)(lds + B1L_OFF + tid * 4) = b1g[tid];
    if (tid < 16) *(float*)(lds + B2L_OFF + tid * 4) = b2g[tid];
    if (tid < 3)  *(float*)(lds + B3L_OFF + tid * 4) = b3g[tid];
    if (tid < 48) *(float*)(lds + W3L_OFF + tid * 4) = w3g[tid];

    __syncthreads();                 // init visible (full drain, once)
    COMMITQ(RA, 0);                  // q0 -> buf0 (vmcnt auto-waited at use)
    __syncthreads();                 // buf0 ready

    f32x4 acc[4][2];

    #pragma unroll 1
    for (int t = 0; t < T; ++t) {
        const int bp = t & 1;
        // ---------------- layer 0: whh0 q0..q3 (A = plane0 old) ----------------
        COMMITQ(RB, bp ^ 1); LOADQ(0, 1, 1, RA);      // commit q1, load q3
        ACC_INIT(0); XPART;
        GATE_HI(0, 0, bp);                            // q0
        BARX;
        COMMITQ(RC, bp); LOADQ(1, 0, 0, RB);          // commit q2, load q4
        GATE_HI(0, 1, bp ^ 1);                        // q1
        BARX;
        COMMITQ(RA, bp ^ 1); LOADQ(1, 1, 0, RC);      // commit q3, load q5
        GATE_LO(0, 0, bp);                            // q2
        BARX;
        COMMITQ(RB, bp); LOADQ(1, 0, 1, RA);          // commit q4, load q6
        GATE_LO(0, 1, bp ^ 1);                        // q3
        BARX;
        CELLW(0, c0);                                 // h0 -> plane0
        BARX;
        // ---------------- layer 1: wih1 q4..q7 (A=plane0 new), whh1 q8..q11 (A=plane1 old) ----------------
        ACC_INIT(1);
        COMMITQ(RC, bp ^ 1); LOADQ(1, 1, 1, RB);      // commit q5, load q7
        GATE_HI(0, 0, bp);                            // q4
        BARX;
        COMMITQ(RA, bp); LOADQ(2, 0, 0, RC);          // commit q6, load q8
        GATE_HI(0, 1, bp ^ 1);                        // q5
        BARX;
        COMMITQ(RB, bp ^ 1); LOADQ(2, 1, 0, RA);      // commit q7, load q9
        GATE_LO(0, 0, bp);                            // q6
        BARX;
        COMMITQ(RC, bp); LOADQ(2, 0, 1, RB);          // commit q8, load q10
        GATE_LO(0, 1, bp ^ 1);                        // q7
        BARX;
        COMMITQ(RA, bp ^ 1); LOADQ(2, 1, 1, RC);      // commit q9, load q11
        GATE_HI(1, 0, bp);                            // q8
        BARX;
        COMMITQ(RB, bp); LOADQ(3, 0, 0, RA);          // commit q10, load q12
        GATE_HI(1, 1, bp ^ 1);                        // q9
        BARX;
        COMMITQ(RC, bp ^ 1); LOADQ(3, 1, 0, RB);      // commit q11, load q13
        GATE_LO(1, 0, bp);                            // q10
        BARX;
        COMMITQ(RA, bp); LOADQ(3, 0, 1, RC);          // commit q12, load q14
        GATE_LO(1, 1, bp ^ 1);                        // q11
        BARX;
        CELLW(1, c1);                                 // h1 -> plane1
        BARX;
        // ---------------- layer 2: wih2 q12..q15 (A=plane1 new), whh2 q16..q19 (A=plane2 old) ----------------
        ACC_INIT(2);
        COMMITQ(RB, bp ^ 1); LOADQ(3, 1, 1, RA);      // commit q13, load q15
        GATE_HI(1, 0, bp);                            // q12
        BARX;
        COMMITQ(RC, bp); LOADQ(4, 0, 0, RB);          // commit q14, load q16
        GATE_HI(1, 1, bp ^ 1);                        // q13
        BARX;
        COMMITQ(RA, bp ^ 1); LOADQ(4, 1, 0, RC);      // commit q15, load q17
        GATE_LO(1, 0, bp);                            // q14
        BARX;
        COMMITQ(RB, bp); LOADQ(4, 0, 1, RA);          // commit q16, load q18
        GATE_LO(1, 1, bp ^ 1);                        // q15
        BARX;
        COMMITQ(RC, bp ^ 1); LOADQ(4, 1, 1, RB);      // commit q17, load q19
        GATE_HI(2, 0, bp);                            // q16
        BARX;
        COMMITQ(RA, bp); LOADW1(RC);                  // commit q18, load q20 (w1)
        GATE_HI(2, 1, bp ^ 1);                        // q17
        BARX;
        COMMITQ(RB, bp ^ 1); LOADQ(0, 0, 0, RA);      // commit q19, load q0'
        GATE_LO(2, 0, bp);                            // q18
        BARX;
        COMMITW1(RC, bp); LOADQ(0, 1, 0, RB);         // commit q20(w1), load q1'
        GATE_LO(2, 1, bp ^ 1);                        // q19
        BARX;
        CELLW(2, c2);                                 // h2 -> plane2
        BARX;
        // ---------------- MLP head ----------------
        COMMITQ(RA, bp ^ 1); LOADQ(0, 0, 1, RC);      // commit q0', load q2'
        MLP1(bp);                                     // y1 via MFMA (A=plane2, B=w1)
        BARX;
        MLP2;                                         // y1 -> y2 (VALU)
        BARX;
        MLP3_OUT;                                     // y2 -> XFB + out ring
        if ((t & 3) == 3) {                           // flush 4 buffered steps
            BARX;
            long tb = t - 3;
            #pragma unroll
            for (int it = 0; it < 2; ++it) {
                int i = it * NTHR + tid;
                if (i < 1536) {
                    int e = i / 12, j = i - e * 12;
                    out[(eg0 + e) * outs + tb * 3 + j] =
                        *(const float*)(lds + OUT_OFF + e * 48 + j * 4);
                }
            }
        }
        BARX;                                         // step boundary
    }

    // tail flush (T not multiple of 4)
    int nst = T & 3;
    if (nst) {
        int nfl = BT * nst * 3;
        for (int i = tid; i < nfl; i += NTHR) {
            int e = i / (nst * 3), j = i - e * (nst * 3);
            out[(eg0 + e) * outs + (long)(T - nst) * 3 + j] =
                *(const float*)(lds + OUT_OFF + e * 48 + j * 4);
        }
    }
}

extern "C" void kernel_launch(void* const* d_in, const int* in_sizes, int n_in,
                              void* d_out, int out_size, void* d_ws, size_t ws_size,
                              hipStream_t stream)
{
    const float* noise = (const float*)d_in[0];
    const float* wih0  = (const float*)d_in[1];
    const float* whh0  = (const float*)d_in[2];
    const float* bih0  = (const float*)d_in[3];
    const float* bhh0  = (const float*)d_in[4];
    const float* wih1  = (const float*)d_in[5];
    const float* whh1  = (const float*)d_in[6];
    const float* bih1  = (const float*)d_in[7];
    const float* bhh1  = (const float*)d_in[8];
    const float* wih2  = (const float*)d_in[9];
    const float* whh2  = (const float*)d_in[10];
    const float* bih2  = (const float*)d_in[11];
    const float* bhh2  = (const float*)d_in[12];
    const float* w1g   = (const float*)d_in[13];
    const float* b1g   = (const float*)d_in[14];
    const float* w2g   = (const float*)d_in[15];
    const float* b2g   = (const float*)d_in[16];
    const float* w3g   = (const float*)d_in[17];
    const float* b3g   = (const float*)d_in[18];
    const int*   lenp  = (const int*)d_in[19];
    float* out = (float*)d_out;

    int B = in_sizes[0] / 3;              // 32768
    int grid = B / BT;                    // 256 blocks = 1 per CU

    prep_weights<<<82, 256, 0, stream>>>(whh0, wih1, whh1, wih2, whh2, w1g);

    hipFuncSetAttribute((const void*)lstm_mfma,
                        hipFuncAttributeMaxDynamicSharedMemorySize, LDS_TOTAL);
    lstm_mfma<<<grid, NTHR, LDS_TOTAL, stream>>>(
        noise, wih0, whh0, bih0, bhh0, wih1, whh1, bih1, bhh1,
        wih2, whh2, bih2, bhh2, w1g, b1g, w2g, b2g, w3g, b3g, lenp, out);
}